// Round 6
// baseline (159.392 us; speedup 1.0000x reference)
//
#include <hip/hip_runtime.h>

#define BB 4
#define CC 64
#define HH 128
#define WW 128
#define NN 16
#define HW (HH*WW)

#if __has_builtin(__builtin_amdgcn_exp2f)
#define EXP2F(x) __builtin_amdgcn_exp2f(x)
#else
#define EXP2F(x) exp2f(x)
#endif

__device__ __forceinline__ float softplus_f(float x) {
    float e = __expf(-fabsf(x));
    return fmaxf(x, 0.0f) + __logf(1.0f + e);
}

// float2 helpers: written so SLP can form v_pk_fma_f32 / v_pk_mul_f32.
__device__ __forceinline__ float2 f2mul(float2 a, float2 b) {
    return make_float2(a.x * b.x, a.y * b.y);
}
__device__ __forceinline__ float2 f2fma(float2 a, float2 b, float2 c) {
    return make_float2(fmaf(a.x, b.x, c.x), fmaf(a.y, b.y, c.y));
}

// ===========================================================================
// Fused proj+scan. grid 1024, block 256 = 64 d x 4 ng (4 SSM states/lane).
// Even blocks: h-scan of row (b,L=h) -> out[b,c,h,:]
// Odd  blocks: v-scan of col (b,L=w) -> yv[b,c,w,:]  ([b][c][w][h])
// R17 = EXACT R0 skeleton (proven 76 VGPR / 79.4us; dlt delta phase +
// 2 barriers/chunk kept — R15/R16 falsified residency & barrier theories)
// with scan ISSUE reduction only:
//  - A pre-scaled by log2e at setup; dA = v_exp directly (saves 4 v_mul/step)
//  - h-update / du*B / y-dot as float2 pairs -> v_pk_* dual fp32
//  - h/v blocks interleaved (bid&1) to balance slow v-gather blocks per CU
// R16 lesson: dur tracks scan VALU issue ~1:1 -> cut issue, not structure.
// ===========================================================================
__global__ __launch_bounds__(256) void k_scan(
    const float* __restrict__ x, const float* __restrict__ xpw,
    const float* __restrict__ A_log, const float* __restrict__ Dv,
    const float* __restrict__ dtw, const float* __restrict__ dtb,
    float* __restrict__ out, float* __restrict__ yv)
{
    __shared__ float xt[128 * 64];   // 32 KB  x line, (j,c) at j*64+((c+j)&63)
    __shared__ float bcs[128 * 32];  // 16 KB  B/C, group g at j*32+((g^(j&7))<<2)
    __shared__ float dtr[128 * 4];   //  2 KB  dt_raw per pixel
    __shared__ float dlt[8 * 64];    //  2 KB  delta chunk [jl][d]

    const int t = threadIdx.x;
    const int half = blockIdx.x & 1;           // interleaved h/v dispatch
    const int r9 = blockIdx.x >> 1;
    const int b = r9 >> 7;
    const int L = r9 & 127;

    // ---- stage x line into swizzled xt ----
    if (half == 0) {
#pragma unroll
        for (int k = 0; k < 8; ++k) {            // rows: float4 coalesced global
            int i = k * 256 + t;
            int c = i >> 5, jq = i & 31;
            float4 v = *(const float4*)&x[((size_t)(b * CC + c) * HH + L) * WW + jq * 4];
            int j0 = jq * 4;
            xt[(j0 + 0) * 64 + ((c + j0 + 0) & 63)] = v.x;
            xt[(j0 + 1) * 64 + ((c + j0 + 1) & 63)] = v.y;
            xt[(j0 + 2) * 64 + ((c + j0 + 2) & 63)] = v.z;
            xt[(j0 + 3) * 64 + ((c + j0 + 3) & 63)] = v.w;
        }
    } else {
#pragma unroll
        for (int p = 0; p < 32; ++p) {           // cols: L2/L3-served gather
            int c = t & 63, j = p * 4 + (t >> 6);
            xt[j * 64 + ((c + j) & 63)] =
                x[((size_t)(b * CC + c) * HH + j) * WW + L];
        }
    }
    __syncthreads();

    // ---- proj: wave pair covers (64 pix) x (18 of 36 cols); xpw uniform ----
    {
        const int wv = t >> 6, lane = t & 63;
        const int pg2 = __builtin_amdgcn_readfirstlane(wv & 1);
        const int pix = (wv >> 1) * 64 + lane;
        const int p0 = pg2 * 18;
        const int sw = pix & 7;
        float acc[18];
#pragma unroll
        for (int j = 0; j < 18; ++j) acc[j] = 0.f;
        for (int c4 = 0; c4 < 16; ++c4) {
            float xv0 = xt[pix * 64 + ((c4 * 4 + 0 + pix) & 63)];
            float xv1 = xt[pix * 64 + ((c4 * 4 + 1 + pix) & 63)];
            float xv2 = xt[pix * 64 + ((c4 * 4 + 2 + pix) & 63)];
            float xv3 = xt[pix * 64 + ((c4 * 4 + 3 + pix) & 63)];
#pragma unroll
            for (int j = 0; j < 18; ++j) {
                float4 wq = *(const float4*)&xpw[(p0 + j) * CC + c4 * 4];
                acc[j] = fmaf(wq.x, xv0, fmaf(wq.y, xv1,
                         fmaf(wq.z, xv2, fmaf(wq.w, xv3, acc[j]))));
            }
        }
        float* bp = &bcs[pix * 32];
        if (pg2 == 0) {
            *(float4*)&dtr[pix * 4] = make_float4(acc[0], acc[1], acc[2], acc[3]);
            // B groups 0..2 full; group 3 split (B12,B13 here)
            *(float4*)&bp[((0 ^ sw) << 2)] = make_float4(acc[4], acc[5], acc[6], acc[7]);
            *(float4*)&bp[((1 ^ sw) << 2)] = make_float4(acc[8], acc[9], acc[10], acc[11]);
            *(float4*)&bp[((2 ^ sw) << 2)] = make_float4(acc[12], acc[13], acc[14], acc[15]);
            bp[((3 ^ sw) << 2) + 0] = acc[16];
            bp[((3 ^ sw) << 2) + 1] = acc[17];
        } else {
            // B14,B15 finish group 3; C groups 4..7 full
            bp[((3 ^ sw) << 2) + 2] = acc[0];
            bp[((3 ^ sw) << 2) + 3] = acc[1];
            *(float4*)&bp[((4 ^ sw) << 2)] = make_float4(acc[2], acc[3], acc[4], acc[5]);
            *(float4*)&bp[((5 ^ sw) << 2)] = make_float4(acc[6], acc[7], acc[8], acc[9]);
            *(float4*)&bp[((6 ^ sw) << 2)] = make_float4(acc[10], acc[11], acc[12], acc[13]);
            *(float4*)&bp[((7 ^ sw) << 2)] = make_float4(acc[14], acc[15], acc[16], acc[17]);
        }
    }

    // ---- scan setup; A pre-scaled by log2e so dA = v_exp directly ----
    const int d = t >> 2, ng = t & 3, n0 = ng * 4;
    const float L2E = 1.44269504088896340736f;
    float A0 = -__expf(A_log[d * NN + n0 + 0]) * L2E;
    float A1 = -__expf(A_log[d * NN + n0 + 1]) * L2E;
    float A2 = -__expf(A_log[d * NN + n0 + 2]) * L2E;
    float A3 = -__expf(A_log[d * NN + n0 + 3]) * L2E;
    const float Dd = Dv[d];
    float2 h01 = make_float2(0.f, 0.f), h23 = make_float2(0.f, 0.f);
    // delta-phase identity: 64 d x (2 j per thread)
    const int dd = t & 63, jb = t >> 6;
    const float4 wt4 = *(const float4*)&dtw[dd * 4];
    const float bdd = dtb[dd];
    float* drow = (half == 0 ? out : yv) + ((size_t)(b * CC + d) * 128 + L) * 128;

    for (int ch = 0; ch < 16; ++ch) {
        __syncthreads();                         // prev chunk's dlt reads done / proj done
        // ---- delta precompute: once per (d,j), 2 j per thread (R0-exact) ----
#pragma unroll
        for (int k = 0; k < 2; ++k) {
            int jl = jb * 2 + k;
            float4 dr = *(const float4*)&dtr[(ch * 8 + jl) * 4];   // bcast
            float draw = fmaf(dr.x, wt4.x, fmaf(dr.y, wt4.y,
                         fmaf(dr.z, wt4.z, fmaf(dr.w, wt4.w, bdd))));
            dlt[jl * 64 + dd] = softplus_f(draw);
        }
        __syncthreads();
        // ---- 8 scan steps, no barriers; pk-paired fp32 ----
        float y0 = 0.f, y1 = 0.f;
#pragma unroll
        for (int jl = 0; jl < 8; ++jl) {
            const int j = ch * 8 + jl;
            float delta = dlt[jl * 64 + d];
            float u = xt[j * 64 + ((d + j) & 63)];
            const int s = j & 7;                 // == jl (compile-time)
            float4 Bv = *(const float4*)&bcs[j * 32 + ((ng ^ s) << 2)];
            float4 Cv = *(const float4*)&bcs[j * 32 + (((4 + ng) ^ s) << 2)];
            float du = delta * u;
            float2 e01 = make_float2(EXP2F(delta * A0), EXP2F(delta * A1));
            float2 e23 = make_float2(EXP2F(delta * A2), EXP2F(delta * A3));
            float2 du2 = make_float2(du, du);
            h01 = f2fma(e01, h01, f2mul(du2, make_float2(Bv.x, Bv.y)));
            h23 = f2fma(e23, h23, f2mul(du2, make_float2(Bv.z, Bv.w)));
            float2 yt = f2fma(h23, make_float2(Cv.z, Cv.w),
                              f2mul(h01, make_float2(Cv.x, Cv.y)));
            float y = yt.x + yt.y;
            y += __shfl_xor(y, 1);               // quad reduction
            y += __shfl_xor(y, 2);
            y = fmaf(u, Dd, y);
            if (ng == (jl >> 1)) { if (jl & 1) y1 = y; else y0 = y; }
        }
        *(float2*)&drow[ch * 8 + ng * 2] = make_float2(y0, y1);
    }
}

// ===========================================================================
// out[b,c,h,w] += yv[b,c,w,h]  (32x32 LDS-tile transposed RMW). R11-proven.
// ===========================================================================
__global__ __launch_bounds__(256) void k_add(const float* __restrict__ yv,
                                             float* __restrict__ out)
{
    __shared__ float td[32 * 33];
    int t = threadIdx.x;
    int bc_ = blockIdx.x >> 4;
    int tb = blockIdx.x & 15;
    int w0 = (tb & 3) * 32;
    int h0 = (tb >> 2) * 32;
    const float* src = yv + (size_t)bc_ * HW;   // [w][h]
    float* dst = out + (size_t)bc_ * HW;        // [h][w]
    int r = t >> 3, q = t & 7;
    float4 v = *(const float4*)&src[(w0 + r) * HH + h0 + q * 4];
    td[r * 33 + q * 4 + 0] = v.x;
    td[r * 33 + q * 4 + 1] = v.y;
    td[r * 33 + q * 4 + 2] = v.z;
    td[r * 33 + q * 4 + 3] = v.w;
    __syncthreads();
    float* op = &dst[(h0 + r) * WW + w0 + q * 4];
    float4 o = *(float4*)op;
    o.x += td[(q * 4 + 0) * 33 + r];
    o.y += td[(q * 4 + 1) * 33 + r];
    o.z += td[(q * 4 + 2) * 33 + r];
    o.w += td[(q * 4 + 3) * 33 + r];
    *(float4*)op = o;
}

// ---------------------------------------------------------------------------
extern "C" void kernel_launch(void* const* d_in, const int* in_sizes, int n_in,
                              void* d_out, int out_size, void* d_ws, size_t ws_size,
                              hipStream_t stream) {
    const float* x     = (const float*)d_in[0];
    const float* A_log = (const float*)d_in[1];
    const float* Dv    = (const float*)d_in[2];
    const float* xpw   = (const float*)d_in[3];
    const float* dtw   = (const float*)d_in[4];
    const float* dtb   = (const float*)d_in[5];
    float* out = (float*)d_out;
    float* yv  = (float*)d_ws;       // 16.8 MB; ws >= 43 MB proven in R11

    k_scan<<<1024, 256, 0, stream>>>(x, xpw, A_log, Dv, dtw, dtb, out, yv);
    k_add <<<BB * CC * 16, 256, 0, stream>>>(yv, out);
}

// Round 7
// 149.928 us; speedup vs baseline: 1.0631x; 1.0631x over previous
//
#include <hip/hip_runtime.h>

#define BB 4
#define CC 64
#define HH 128
#define WW 128
#define NN 16
#define HW (HH*WW)

#if __has_builtin(__builtin_amdgcn_exp2f)
#define EXP2F(x) __builtin_amdgcn_exp2f(x)
#else
#define EXP2F(x) exp2f(x)
#endif

__device__ __forceinline__ float softplus_f(float x) {
    float e = __expf(-fabsf(x));
    return fmaxf(x, 0.0f) + __logf(1.0f + e);
}

// float2 helpers: written so SLP can form v_pk_fma_f32 / v_pk_mul_f32.
__device__ __forceinline__ float2 f2mul(float2 a, float2 b) {
    return make_float2(a.x * b.x, a.y * b.y);
}
__device__ __forceinline__ float2 f2fma(float2 a, float2 b, float2 c) {
    return make_float2(fmaf(a.x, b.x, c.x), fmaf(a.y, b.y, c.y));
}

// ===========================================================================
// Fused proj+scan. grid 1024, block 256 = 64 d x 4 ng (4 SSM states/lane).
// Blocks [0,512): h-scan of row (b,L=h) -> out[b,c,h,:]
// Blocks [512,1024): v-scan of col (b,L=w) -> yv[b,c,w,:]  ([b][c][w][h])
// R18 = R17 scan body (exp2-folded A, pk float2 pairs, dlt delta phase,
// 2 barriers/chunk) with the h/v mapping REVERTED to R0's half = bid>>9.
// R17 lesson: bid&1 parity-clusters blocks per CU (round-robin gives CU i
// blocks {i,i+256,i+512,i+768}, all same parity) -> half the CUs got 4 slow
// v-gather blocks and became the critical path (FETCH -43% from clustering
// L2 reuse, dur +12%). R0's bid>>9 is already 2h+2v per CU. This round
// isolates the exp2/pk issue cut against the 79.4us baseline.
// ===========================================================================
__global__ __launch_bounds__(256) void k_scan(
    const float* __restrict__ x, const float* __restrict__ xpw,
    const float* __restrict__ A_log, const float* __restrict__ Dv,
    const float* __restrict__ dtw, const float* __restrict__ dtb,
    float* __restrict__ out, float* __restrict__ yv)
{
    __shared__ float xt[128 * 64];   // 32 KB  x line, (j,c) at j*64+((c+j)&63)
    __shared__ float bcs[128 * 32];  // 16 KB  B/C, group g at j*32+((g^(j&7))<<2)
    __shared__ float dtr[128 * 4];   //  2 KB  dt_raw per pixel
    __shared__ float dlt[8 * 64];    //  2 KB  delta chunk [jl][d]

    const int t = threadIdx.x;
    const int half = blockIdx.x >> 9;          // R0-proven balanced mapping
    const int r9 = blockIdx.x & 511;
    const int b = r9 >> 7;
    const int L = r9 & 127;

    // ---- stage x line into swizzled xt ----
    if (half == 0) {
#pragma unroll
        for (int k = 0; k < 8; ++k) {            // rows: float4 coalesced global
            int i = k * 256 + t;
            int c = i >> 5, jq = i & 31;
            float4 v = *(const float4*)&x[((size_t)(b * CC + c) * HH + L) * WW + jq * 4];
            int j0 = jq * 4;
            xt[(j0 + 0) * 64 + ((c + j0 + 0) & 63)] = v.x;
            xt[(j0 + 1) * 64 + ((c + j0 + 1) & 63)] = v.y;
            xt[(j0 + 2) * 64 + ((c + j0 + 2) & 63)] = v.z;
            xt[(j0 + 3) * 64 + ((c + j0 + 3) & 63)] = v.w;
        }
    } else {
#pragma unroll
        for (int p = 0; p < 32; ++p) {           // cols: L2/L3-served gather
            int c = t & 63, j = p * 4 + (t >> 6);
            xt[j * 64 + ((c + j) & 63)] =
                x[((size_t)(b * CC + c) * HH + j) * WW + L];
        }
    }
    __syncthreads();

    // ---- proj: wave pair covers (64 pix) x (18 of 36 cols); xpw uniform ----
    {
        const int wv = t >> 6, lane = t & 63;
        const int pg2 = __builtin_amdgcn_readfirstlane(wv & 1);
        const int pix = (wv >> 1) * 64 + lane;
        const int p0 = pg2 * 18;
        const int sw = pix & 7;
        float acc[18];
#pragma unroll
        for (int j = 0; j < 18; ++j) acc[j] = 0.f;
        for (int c4 = 0; c4 < 16; ++c4) {
            float xv0 = xt[pix * 64 + ((c4 * 4 + 0 + pix) & 63)];
            float xv1 = xt[pix * 64 + ((c4 * 4 + 1 + pix) & 63)];
            float xv2 = xt[pix * 64 + ((c4 * 4 + 2 + pix) & 63)];
            float xv3 = xt[pix * 64 + ((c4 * 4 + 3 + pix) & 63)];
#pragma unroll
            for (int j = 0; j < 18; ++j) {
                float4 wq = *(const float4*)&xpw[(p0 + j) * CC + c4 * 4];
                acc[j] = fmaf(wq.x, xv0, fmaf(wq.y, xv1,
                         fmaf(wq.z, xv2, fmaf(wq.w, xv3, acc[j]))));
            }
        }
        float* bp = &bcs[pix * 32];
        if (pg2 == 0) {
            *(float4*)&dtr[pix * 4] = make_float4(acc[0], acc[1], acc[2], acc[3]);
            // B groups 0..2 full; group 3 split (B12,B13 here)
            *(float4*)&bp[((0 ^ sw) << 2)] = make_float4(acc[4], acc[5], acc[6], acc[7]);
            *(float4*)&bp[((1 ^ sw) << 2)] = make_float4(acc[8], acc[9], acc[10], acc[11]);
            *(float4*)&bp[((2 ^ sw) << 2)] = make_float4(acc[12], acc[13], acc[14], acc[15]);
            bp[((3 ^ sw) << 2) + 0] = acc[16];
            bp[((3 ^ sw) << 2) + 1] = acc[17];
        } else {
            // B14,B15 finish group 3; C groups 4..7 full
            bp[((3 ^ sw) << 2) + 2] = acc[0];
            bp[((3 ^ sw) << 2) + 3] = acc[1];
            *(float4*)&bp[((4 ^ sw) << 2)] = make_float4(acc[2], acc[3], acc[4], acc[5]);
            *(float4*)&bp[((5 ^ sw) << 2)] = make_float4(acc[6], acc[7], acc[8], acc[9]);
            *(float4*)&bp[((6 ^ sw) << 2)] = make_float4(acc[10], acc[11], acc[12], acc[13]);
            *(float4*)&bp[((7 ^ sw) << 2)] = make_float4(acc[14], acc[15], acc[16], acc[17]);
        }
    }

    // ---- scan setup; A pre-scaled by log2e so dA = v_exp directly ----
    const int d = t >> 2, ng = t & 3, n0 = ng * 4;
    const float L2E = 1.44269504088896340736f;
    float A0 = -__expf(A_log[d * NN + n0 + 0]) * L2E;
    float A1 = -__expf(A_log[d * NN + n0 + 1]) * L2E;
    float A2 = -__expf(A_log[d * NN + n0 + 2]) * L2E;
    float A3 = -__expf(A_log[d * NN + n0 + 3]) * L2E;
    const float Dd = Dv[d];
    float2 h01 = make_float2(0.f, 0.f), h23 = make_float2(0.f, 0.f);
    // delta-phase identity: 64 d x (2 j per thread)
    const int dd = t & 63, jb = t >> 6;
    const float4 wt4 = *(const float4*)&dtw[dd * 4];
    const float bdd = dtb[dd];
    float* drow = (half == 0 ? out : yv) + ((size_t)(b * CC + d) * 128 + L) * 128;

    for (int ch = 0; ch < 16; ++ch) {
        __syncthreads();                         // prev chunk's dlt reads done / proj done
        // ---- delta precompute: once per (d,j), 2 j per thread (R0-exact) ----
#pragma unroll
        for (int k = 0; k < 2; ++k) {
            int jl = jb * 2 + k;
            float4 dr = *(const float4*)&dtr[(ch * 8 + jl) * 4];   // bcast
            float draw = fmaf(dr.x, wt4.x, fmaf(dr.y, wt4.y,
                         fmaf(dr.z, wt4.z, fmaf(dr.w, wt4.w, bdd))));
            dlt[jl * 64 + dd] = softplus_f(draw);
        }
        __syncthreads();
        // ---- 8 scan steps, no barriers; pk-paired fp32 ----
        float y0 = 0.f, y1 = 0.f;
#pragma unroll
        for (int jl = 0; jl < 8; ++jl) {
            const int j = ch * 8 + jl;
            float delta = dlt[jl * 64 + d];
            float u = xt[j * 64 + ((d + j) & 63)];
            const int s = j & 7;                 // == jl (compile-time)
            float4 Bv = *(const float4*)&bcs[j * 32 + ((ng ^ s) << 2)];
            float4 Cv = *(const float4*)&bcs[j * 32 + (((4 + ng) ^ s) << 2)];
            float du = delta * u;
            float2 e01 = make_float2(EXP2F(delta * A0), EXP2F(delta * A1));
            float2 e23 = make_float2(EXP2F(delta * A2), EXP2F(delta * A3));
            float2 du2 = make_float2(du, du);
            h01 = f2fma(e01, h01, f2mul(du2, make_float2(Bv.x, Bv.y)));
            h23 = f2fma(e23, h23, f2mul(du2, make_float2(Bv.z, Bv.w)));
            float2 yt = f2fma(h23, make_float2(Cv.z, Cv.w),
                              f2mul(h01, make_float2(Cv.x, Cv.y)));
            float y = yt.x + yt.y;
            y += __shfl_xor(y, 1);               // quad reduction
            y += __shfl_xor(y, 2);
            y = fmaf(u, Dd, y);
            if (ng == (jl >> 1)) { if (jl & 1) y1 = y; else y0 = y; }
        }
        *(float2*)&drow[ch * 8 + ng * 2] = make_float2(y0, y1);
    }
}

// ===========================================================================
// out[b,c,h,w] += yv[b,c,w,h]  (32x32 LDS-tile transposed RMW). R11-proven.
// ===========================================================================
__global__ __launch_bounds__(256) void k_add(const float* __restrict__ yv,
                                             float* __restrict__ out)
{
    __shared__ float td[32 * 33];
    int t = threadIdx.x;
    int bc_ = blockIdx.x >> 4;
    int tb = blockIdx.x & 15;
    int w0 = (tb & 3) * 32;
    int h0 = (tb >> 2) * 32;
    const float* src = yv + (size_t)bc_ * HW;   // [w][h]
    float* dst = out + (size_t)bc_ * HW;        // [h][w]
    int r = t >> 3, q = t & 7;
    float4 v = *(const float4*)&src[(w0 + r) * HH + h0 + q * 4];
    td[r * 33 + q * 4 + 0] = v.x;
    td[r * 33 + q * 4 + 1] = v.y;
    td[r * 33 + q * 4 + 2] = v.z;
    td[r * 33 + q * 4 + 3] = v.w;
    __syncthreads();
    float* op = &dst[(h0 + r) * WW + w0 + q * 4];
    float4 o = *(float4*)op;
    o.x += td[(q * 4 + 0) * 33 + r];
    o.y += td[(q * 4 + 1) * 33 + r];
    o.z += td[(q * 4 + 2) * 33 + r];
    o.w += td[(q * 4 + 3) * 33 + r];
    *(float4*)op = o;
}

// ---------------------------------------------------------------------------
extern "C" void kernel_launch(void* const* d_in, const int* in_sizes, int n_in,
                              void* d_out, int out_size, void* d_ws, size_t ws_size,
                              hipStream_t stream) {
    const float* x     = (const float*)d_in[0];
    const float* A_log = (const float*)d_in[1];
    const float* Dv    = (const float*)d_in[2];
    const float* xpw   = (const float*)d_in[3];
    const float* dtw   = (const float*)d_in[4];
    const float* dtb   = (const float*)d_in[5];
    float* out = (float*)d_out;
    float* yv  = (float*)d_ws;       // 16.8 MB; ws >= 43 MB proven in R11

    k_scan<<<1024, 256, 0, stream>>>(x, xpw, A_log, Dv, dtw, dtb, out, yv);
    k_add <<<BB * CC * 16, 256, 0, stream>>>(yv, out);
}